// Round 1
// baseline (843.690 us; speedup 1.0000x reference)
//
#include <hip/hip_runtime.h>

// Problem constants (static per setup_inputs)
#define BB 4
#define SS 2048
#define DD 2048
#define HH 16
#define DHD 128
#define MAXL 1024

typedef __bf16 bf16x8 __attribute__((ext_vector_type(8)));
typedef float f32x4 __attribute__((ext_vector_type(4)));
typedef unsigned int u32_as1 __attribute__((address_space(1)));
typedef unsigned int u32_as3 __attribute__((address_space(3)));

__device__ __forceinline__ unsigned short f2bf(float f) {
  unsigned int u = __builtin_bit_cast(unsigned int, f);
  u += 0x7fffu + ((u >> 16) & 1u);   // RNE
  return (unsigned short)(u >> 16);
}
__device__ __forceinline__ float bf2f(unsigned short h) {
  unsigned int u = ((unsigned int)h) << 16;
  return __builtin_bit_cast(float, u);
}
union U4 { uint4 u; bf16x8 b; };
__device__ __forceinline__ bf16x8 ldfrag(const unsigned short* p) {
  U4 x; x.u = *(const uint4*)p; return x.b;
}
__device__ __forceinline__ void gl_lds16(const void* g, void* l) {
  // async global->LDS, width 16B/lane; LDS dest = wave-uniform base + lane*16
  __builtin_amdgcn_global_load_lds((const u32_as1*)g, (u32_as3*)l, 16, 0, 0);
}

// ---------------------------------------------------------------------------
// pos_trim / n_valid from skip_mask (bool delivered as int32).
// posk[b][l] = original index s of the l-th kept position (ascending), -1 pad.
__global__ void build_pos(const int* __restrict__ skip, int* __restrict__ posk,
                          int* __restrict__ nval) {
  int b = blockIdx.x, t = threadIdx.x;  // 64 threads = 1 wave
  __shared__ int cnts[64], offs[64];
  const int* row = skip + b * SS;
  int c = 0;
  for (int i = 0; i < 32; i++) c += (row[t * 32 + i] != 0);
  cnts[t] = c;
  __syncthreads();
  if (t == 0) {
    int run = 0;
    for (int i = 0; i < 64; i++) { offs[i] = run; run += cnts[i]; }
    nval[b] = run > MAXL ? MAXL : run;
  }
  __syncthreads();
  int o = offs[t];
  for (int i = 0; i < 32; i++)
    if (row[t * 32 + i]) { if (o < MAXL) posk[b * MAXL + o] = t * 32 + i; o++; }
  int nb = nval[b];
  for (int l = nb + t; l < MAXL; l += 64) posk[b * MAXL + l] = -1;
}

// ---------------------------------------------------------------------------
// fp32 -> bf16 elementwise (n % 4 == 0)
__global__ __launch_bounds__(256) void cvt_bf16(const float* __restrict__ in,
                                                unsigned short* __restrict__ out, int n) {
  int idx = (blockIdx.x * 256 + threadIdx.x) * 4;
  int stride = gridDim.x * 256 * 4;
  for (; idx < n; idx += stride) {
    float4 v = *(const float4*)&in[idx];
    ushort4 h;
    h.x = f2bf(v.x); h.y = f2bf(v.y); h.z = f2bf(v.z); h.w = f2bf(v.w);
    *(ushort4*)&out[idx] = h;
  }
}

// ---------------------------------------------------------------------------
// W [K][N] fp32 -> Wt [N][K] bf16 via 64x64 LDS tile (one-time cost; phase-2
// scalar reads have ~8-way conflicts — acceptable, flagged for later).
__global__ __launch_bounds__(256) void transpose_bf16(const float* __restrict__ W,
                                                      unsigned short* __restrict__ Wt,
                                                      int Kdim, int Ndim) {
  __shared__ __align__(16) unsigned short tile[64 * 76];
  int tx = threadIdx.x;
  int K0 = blockIdx.y * 64, N0 = blockIdx.x * 64;
  #pragma unroll
  for (int i = 0; i < 4; i++) {
    int r = (tx >> 4) + i * 16;      // k-local
    int c4 = (tx & 15) * 4;          // n-local
    float4 v = *(const float4*)&W[(size_t)(K0 + r) * Ndim + N0 + c4];
    ushort4 h;
    h.x = f2bf(v.x); h.y = f2bf(v.y); h.z = f2bf(v.z); h.w = f2bf(v.w);
    *(ushort4*)&tile[r * 76 + c4] = h;
  }
  __syncthreads();
  #pragma unroll
  for (int i = 0; i < 4; i++) {
    int n = (tx >> 4) + i * 16;      // n-local
    int k4 = (tx & 15) * 4;          // k-local
    ushort4 h;
    h.x = tile[(k4 + 0) * 76 + n];
    h.y = tile[(k4 + 1) * 76 + n];
    h.z = tile[(k4 + 2) * 76 + n];
    h.w = tile[(k4 + 3) * 76 + n];
    *(ushort4*)&Wt[(size_t)(N0 + n) * Kdim + K0 + k4] = h;
  }
}

// ---------------------------------------------------------------------------
// m97-style bf16 GEMM: C[m][n] = sum_k A[m][k] * Bt[n][k], 128x128 tile, BK=32,
// 4 waves x (64x64), 16x16x32 MFMA, global_load_lds width-16 staging.
// mode 0: write bf16 to head-split [b][h][l][128] (Lrows = 1<<Lbits)
// mode 1: write fp32 row-major [M][N]
__global__ __launch_bounds__(256) void gemm_bt(const unsigned short* __restrict__ A,
                                               const unsigned short* __restrict__ Bt,
                                               void* __restrict__ Cp,
                                               int M, int N, int K, int mode, int Lbits) {
  __shared__ __align__(16) unsigned short As[128 * 32];
  __shared__ __align__(16) unsigned short Bs[128 * 32];
  const int tid = threadIdx.x;
  const int lane = tid & 63, quad = lane >> 4, c = lane & 15;
  const int w = tid >> 6;
  const int wm = (w >> 1) * 64, wn = (w & 1) * 64;
  const size_t tm = (size_t)blockIdx.y * 128, tn = (size_t)blockIdx.x * 128;

  f32x4 acc[4][4] = {};

  const int srow = tid >> 2, scol = (tid & 3) * 8;
  const unsigned short* ga = A + (tm + srow) * K + scol;
  const unsigned short* gb = Bt + (tn + srow) * K + scol;
  unsigned short* la = &As[tid * 8];
  unsigned short* lb = &Bs[tid * 8];

  for (int kk = 0; kk < K; kk += 32) {
    gl_lds16(ga + kk, la);
    gl_lds16(ga + kk + (size_t)64 * K, la + 2048);
    gl_lds16(gb + kk, lb);
    gl_lds16(gb + kk + (size_t)64 * K, lb + 2048);
    __syncthreads();   // drains vmcnt (compiler inserts s_waitcnt before s_barrier)
    bf16x8 af[4], bfr[4];
    #pragma unroll
    for (int i = 0; i < 4; i++) af[i] = ldfrag(&As[(wm + i * 16 + c) * 32 + quad * 8]);
    #pragma unroll
    for (int j = 0; j < 4; j++) bfr[j] = ldfrag(&Bs[(wn + j * 16 + c) * 32 + quad * 8]);
    #pragma unroll
    for (int i = 0; i < 4; i++)
      #pragma unroll
      for (int j = 0; j < 4; j++)
        acc[i][j] = __builtin_amdgcn_mfma_f32_16x16x32_bf16(af[i], bfr[j], acc[i][j], 0, 0, 0);
    __syncthreads();
  }

  // C/D layout (verified m89/m91): col = lane&15, row = quad*4 + reg
  if (mode == 0) {
    unsigned short* Cb = (unsigned short*)Cp;
    const size_t Lmask = ((size_t)1 << Lbits) - 1;
    #pragma unroll
    for (int i = 0; i < 4; i++)
      #pragma unroll
      for (int j = 0; j < 4; j++)
        #pragma unroll
        for (int r = 0; r < 4; r++) {
          size_t m = tm + wm + i * 16 + quad * 4 + r;
          size_t n = tn + wn + j * 16 + c;
          size_t b = m >> Lbits, l = m & Lmask;
          size_t h = n >> 7, d = n & 127;
          Cb[(((b * HH + h) << Lbits) + l) * 128 + d] = f2bf(acc[i][j][r]);
        }
  } else {
    float* Cf = (float*)Cp;
    #pragma unroll
    for (int i = 0; i < 4; i++)
      #pragma unroll
      for (int j = 0; j < 4; j++)
        #pragma unroll
        for (int r = 0; r < 4; r++) {
          size_t m = tm + wm + i * 16 + quad * 4 + r;
          size_t n = tn + wn + j * 16 + c;
          Cf[m * N + n] = acc[i][j][r];
        }
  }
}

// ---------------------------------------------------------------------------
// In-place RoPE on [B][H][L][128] bf16. use_posk: pos = posk[b][l] (Q), else pos = l (K).
__global__ __launch_bounds__(256) void rope_kernel(unsigned short* __restrict__ x,
                                                   const int* __restrict__ posk,
                                                   int Lbits, int use_posk) {
  int idx = blockIdx.x * 256 + threadIdx.x;
  int d = idx & 63;
  int rest = idx >> 6;                 // = bh*L + l
  int l = rest & ((1 << Lbits) - 1);
  int bh = rest >> Lbits;
  int b = bh >> 4;
  int p = use_posk ? posk[(b << 10) + l] : l;  // -1 on invalid rows: discarded later
  float ang = (float)p * __expf(-(float)d * 0.14391156831212787f); // ln(1e4)/64
  float sn, cs;
  __sincosf(ang, &sn, &cs);
  size_t base = (size_t)rest * 128;
  float x1 = bf2f(x[base + d]), x2 = bf2f(x[base + d + 64]);
  x[base + d]      = f2bf(x1 * cs - x2 * sn);
  x[base + d + 64] = f2bf(x2 * cs + x1 * sn);
}

// ---------------------------------------------------------------------------
// Flash attention. Grid: (qtile 16, bh 64). 256 thr = 4 waves; wave w owns 16 q rows.
// Per K-tile (64 keys): S = Q K^T (16 MFMA/wave), online softmax, P->LDS->A-frag,
// O += P V (16 MFMA/wave, V transposed in LDS). Causal cutoff: key <= posk[l].
__global__ __launch_bounds__(256) void attn_kernel(const unsigned short* __restrict__ qp,
                                                   const unsigned short* __restrict__ kp,
                                                   const unsigned short* __restrict__ vp,
                                                   const int* __restrict__ posk,
                                                   const int* __restrict__ nval,
                                                   unsigned short* __restrict__ ctx) {
  __shared__ __align__(16) unsigned short q_s[64 * 136];   // stride 136: 2-way banks
  __shared__ __align__(16) unsigned short k_s[64 * 136];
  __shared__ __align__(16) unsigned short vt_s[128 * 72];  // V^T [d][s], stride 72
  __shared__ __align__(16) unsigned short p_s[4 * 16 * 72];
  __shared__ int km_s[64];

  const int tid = threadIdx.x;
  const int w = tid >> 6, lane = tid & 63, quad = lane >> 4, c = lane & 15;
  const int bh = blockIdx.y, b = bh >> 4, h = bh & 15;
  const int qbase = blockIdx.x * 64;
  const int nb = nval[b];

  const unsigned short* qg = qp + (((size_t)bh << 10) + qbase) * 128;
  const unsigned short* kg = kp + ((size_t)bh << 11) * 128;
  const unsigned short* vg = vp + ((size_t)bh << 11) * 128;

  if (tid < 64) {
    int l = qbase + tid;
    km_s[tid] = (l < nb) ? posk[(b << 10) + l] : -1;
  }
  {
    int r = tid >> 4, c8 = (tid & 15) * 8;
    #pragma unroll
    for (int i = 0; i < 4; i++)
      *(uint4*)&q_s[(r + i * 16) * 136 + c8] = *(const uint4*)&qg[(size_t)(r + i * 16) * 128 + c8];
  }
  __syncthreads();

  int lv = nb - 1 - qbase; lv = lv > 63 ? 63 : lv;
  const int tile_kmax = (lv >= 0) ? km_s[lv] : -1;  // positions ascending -> last valid row is max
  const int nkt = (tile_kmax >= 0) ? ((tile_kmax >> 6) + 1) : 0;

  int km[4];
  #pragma unroll
  for (int r = 0; r < 4; r++) km[r] = km_s[w * 16 + quad * 4 + r];

  float m_i[4], l_i[4];
  #pragma unroll
  for (int r = 0; r < 4; r++) { m_i[r] = -1e30f; l_i[r] = 0.f; }
  f32x4 o[8];
  #pragma unroll
  for (int dj = 0; dj < 8; dj++) o[dj] = (f32x4){0.f, 0.f, 0.f, 0.f};

  for (int kt = 0; kt < nkt; kt++) {
    const int kb = kt * 64;
    __syncthreads();   // prev iteration's LDS reads done before overwrite
    {
      int r = tid >> 4, c8 = (tid & 15) * 8;
      #pragma unroll
      for (int i = 0; i < 4; i++)
        *(uint4*)&k_s[(r + i * 16) * 136 + c8] =
            *(const uint4*)&kg[(size_t)(kb + r + i * 16) * 128 + c8];
      int s = tid & 63, dbase = (tid >> 6) * 8;
      #pragma unroll
      for (int i = 0; i < 4; i++) {
        int d0 = dbase + i * 32;
        uint4 vv = *(const uint4*)&vg[(size_t)(kb + s) * 128 + d0];
        unsigned short* ep = (unsigned short*)&vv;
        #pragma unroll
        for (int j = 0; j < 8; j++) vt_s[(d0 + j) * 72 + s] = ep[j];
      }
    }
    __syncthreads();

    // S = Q K^T
    bf16x8 aq[4];
    #pragma unroll
    for (int ks = 0; ks < 4; ks++) aq[ks] = ldfrag(&q_s[(w * 16 + c) * 136 + ks * 32 + quad * 8]);
    f32x4 sa[4];
    #pragma unroll
    for (int j = 0; j < 4; j++) {
      sa[j] = (f32x4){0.f, 0.f, 0.f, 0.f};
      #pragma unroll
      for (int ks = 0; ks < 4; ks++) {
        bf16x8 bk = ldfrag(&k_s[(j * 16 + c) * 136 + ks * 32 + quad * 8]);
        sa[j] = __builtin_amdgcn_mfma_f32_16x16x32_bf16(aq[ks], bk, sa[j], 0, 0, 0);
      }
    }

    // online softmax over this key tile; row r of quad <-> C-row quad*4+r
    const float scale = 0.08838834764831843f;  // 1/sqrt(128)
    float mt[4] = {-1e30f, -1e30f, -1e30f, -1e30f};
    #pragma unroll
    for (int j = 0; j < 4; j++) {
      int key = kb + j * 16 + c;
      #pragma unroll
      for (int r = 0; r < 4; r++) {
        float v = (key <= km[r]) ? sa[j][r] * scale : -1e30f;
        sa[j][r] = v;
        mt[r] = fmaxf(mt[r], v);
      }
    }
    #pragma unroll
    for (int r = 0; r < 4; r++)
      for (int off = 1; off < 16; off <<= 1)
        mt[r] = fmaxf(mt[r], __shfl_xor(mt[r], off, 16));
    float al[4], rs[4];
    #pragma unroll
    for (int r = 0; r < 4; r++) {
      float mn = fmaxf(m_i[r], mt[r]);
      al[r] = __expf(m_i[r] - mn);
      m_i[r] = mn;
      rs[r] = 0.f;
    }
    #pragma unroll
    for (int j = 0; j < 4; j++)
      #pragma unroll
      for (int r = 0; r < 4; r++) {
        float pv = __expf(sa[j][r] - m_i[r]);
        sa[j][r] = pv;
        rs[r] += pv;
      }
    #pragma unroll
    for (int r = 0; r < 4; r++) {
      for (int off = 1; off < 16; off <<= 1) rs[r] += __shfl_xor(rs[r], off, 16);
      l_i[r] = l_i[r] * al[r] + rs[r];
    }
    #pragma unroll
    for (int dj = 0; dj < 8; dj++)
      #pragma unroll
      for (int r = 0; r < 4; r++) o[dj][r] *= al[r];

    // P: C-layout -> LDS -> A-layout (per-wave private region; no barrier needed)
    #pragma unroll
    for (int j = 0; j < 4; j++)
      #pragma unroll
      for (int r = 0; r < 4; r++)
        p_s[w * 1152 + (quad * 4 + r) * 72 + j * 16 + c] = f2bf(sa[j][r]);

    #pragma unroll
    for (int ks2 = 0; ks2 < 2; ks2++) {
      bf16x8 ap = ldfrag(&p_s[w * 1152 + c * 72 + ks2 * 32 + quad * 8]);
      #pragma unroll
      for (int dj = 0; dj < 8; dj++) {
        bf16x8 bv = ldfrag(&vt_s[(dj * 16 + c) * 72 + ks2 * 32 + quad * 8]);
        o[dj] = __builtin_amdgcn_mfma_f32_16x16x32_bf16(ap, bv, o[dj], 0, 0, 0);
      }
    }
  }

  // epilogue: normalize, zero invalid rows, write ctx [b][l][h*128+d] bf16
  #pragma unroll
  for (int r = 0; r < 4; r++) {
    int l = qbase + w * 16 + quad * 4 + r;
    bool ok = (l < nb);
    float inv = ok ? (1.0f / l_i[r]) : 0.0f;
    #pragma unroll
    for (int dj = 0; dj < 8; dj++)
      ctx[(((size_t)b << 10) + l) * (size_t)DD + h * 128 + dj * 16 + c] =
          f2bf(ok ? o[dj][r] * inv : 0.0f);
  }
}

// ---------------------------------------------------------------------------
extern "C" void kernel_launch(void* const* d_in, const int* in_sizes, int n_in,
                              void* d_out, int out_size, void* d_ws, size_t ws_size,
                              hipStream_t stream) {
  const float* q_src = (const float*)d_in[0];
  const float* k_src = (const float*)d_in[1];
  const float* v_src = (const float*)d_in[2];
  const float* Wq = (const float*)d_in[3];
  const float* Wk = (const float*)d_in[4];
  const float* Wv = (const float*)d_in[5];
  const float* Wo = (const float*)d_in[6];
  // d_in[7] = mask0 (causal tril; structure assumed), d_in[8] = pos_full (= arange; assumed)
  const int* skip = (const int*)d_in[9];

  char* p = (char*)d_ws;
  auto alloc = [&](size_t bytes) -> char* {
    char* r = p;
    p += (bytes + 255) & ~(size_t)255;
    return r;
  };
  unsigned short* a_q  = (unsigned short*)alloc((size_t)BB * MAXL * DD * 2);  // 16 MB
  unsigned short* a_k  = (unsigned short*)alloc((size_t)BB * SS * DD * 2);    // 32 MB
  unsigned short* a_v  = (unsigned short*)alloc((size_t)BB * SS * DD * 2);    // 32 MB
  unsigned short* wt_q = (unsigned short*)alloc((size_t)DD * DD * 2);
  unsigned short* wt_k = (unsigned short*)alloc((size_t)DD * DD * 2);
  unsigned short* wt_v = (unsigned short*)alloc((size_t)DD * DD * 2);
  unsigned short* wt_o = (unsigned short*)alloc((size_t)DD * DD * 2);
  unsigned short* q_pro = (unsigned short*)alloc((size_t)BB * HH * MAXL * DHD * 2);
  unsigned short* k_pro = (unsigned short*)alloc((size_t)BB * HH * SS * DHD * 2);
  unsigned short* v_pro = (unsigned short*)alloc((size_t)BB * HH * SS * DHD * 2);
  int* posk = (int*)alloc((size_t)BB * MAXL * 4);
  int* nval = (int*)alloc(64);
  unsigned short* ctx = a_q;  // a_q dead after Q projection; reuse for ctx

  build_pos<<<BB, 64, 0, stream>>>(skip, posk, nval);
  cvt_bf16<<<4096, 256, 0, stream>>>(q_src, a_q, BB * MAXL * DD);
  cvt_bf16<<<4096, 256, 0, stream>>>(k_src, a_k, BB * SS * DD);
  cvt_bf16<<<4096, 256, 0, stream>>>(v_src, a_v, BB * SS * DD);
  transpose_bf16<<<dim3(32, 32), 256, 0, stream>>>(Wq, wt_q, DD, DD);
  transpose_bf16<<<dim3(32, 32), 256, 0, stream>>>(Wk, wt_k, DD, DD);
  transpose_bf16<<<dim3(32, 32), 256, 0, stream>>>(Wv, wt_v, DD, DD);
  transpose_bf16<<<dim3(32, 32), 256, 0, stream>>>(Wo, wt_o, DD, DD);

  gemm_bt<<<dim3(16, 32), 256, 0, stream>>>(a_q, wt_q, q_pro, BB * MAXL, DD, DD, 0, 10);
  gemm_bt<<<dim3(16, 64), 256, 0, stream>>>(a_k, wt_k, k_pro, BB * SS, DD, DD, 0, 11);
  gemm_bt<<<dim3(16, 64), 256, 0, stream>>>(a_v, wt_v, v_pro, BB * SS, DD, DD, 0, 11);

  rope_kernel<<<(BB * HH * MAXL * 64) / 256, 256, 0, stream>>>(q_pro, posk, 10, 1);
  rope_kernel<<<(BB * HH * SS * 64) / 256, 256, 0, stream>>>(k_pro, posk, 11, 0);

  attn_kernel<<<dim3(MAXL / 64, BB * HH), 256, 0, stream>>>(q_pro, k_pro, v_pro, posk, nval, ctx);

  gemm_bt<<<dim3(16, 32), 256, 0, stream>>>(ctx, wt_o, d_out, BB * MAXL, DD, DD, 1, 0);
}

// Round 2
// 762.060 us; speedup vs baseline: 1.1071x; 1.1071x over previous
//
#include <hip/hip_runtime.h>

#define BB 4
#define SS 2048
#define DD 2048
#define HH 16
#define DHD 128
#define MAXL 1024

typedef __bf16 bf16x8 __attribute__((ext_vector_type(8)));
typedef float f32x4 __attribute__((ext_vector_type(4)));
typedef unsigned int u32_as1 __attribute__((address_space(1)));
typedef unsigned int u32_as3 __attribute__((address_space(3)));

__device__ __forceinline__ unsigned short f2bf(float f) {
  unsigned int u = __builtin_bit_cast(unsigned int, f);
  u += 0x7fffu + ((u >> 16) & 1u);   // RNE
  return (unsigned short)(u >> 16);
}
__device__ __forceinline__ float bf2f(unsigned short h) {
  unsigned int u = ((unsigned int)h) << 16;
  return __builtin_bit_cast(float, u);
}
union U4 { uint4 u; bf16x8 b; };
__device__ __forceinline__ bf16x8 ldfrag(const unsigned short* p) {
  U4 x; x.u = *(const uint4*)p; return x.b;
}
__device__ __forceinline__ void gl_lds16(const void* g, void* l) {
  __builtin_amdgcn_global_load_lds((const u32_as1*)g, (u32_as3*)l, 16, 0, 0);
}

// ---------------------------------------------------------------------------
__global__ void build_pos(const int* __restrict__ skip, int* __restrict__ posk,
                          int* __restrict__ nval) {
  int b = blockIdx.x, t = threadIdx.x;  // 64 threads
  __shared__ int cnts[64], offs[64];
  const int* row = skip + b * SS;
  int c = 0;
  for (int i = 0; i < 32; i++) c += (row[t * 32 + i] != 0);
  cnts[t] = c;
  __syncthreads();
  if (t == 0) {
    int run = 0;
    for (int i = 0; i < 64; i++) { offs[i] = run; run += cnts[i]; }
    nval[b] = run > MAXL ? MAXL : run;
  }
  __syncthreads();
  int o = offs[t];
  for (int i = 0; i < 32; i++)
    if (row[t * 32 + i]) { if (o < MAXL) posk[b * MAXL + o] = t * 32 + i; o++; }
  int nb = nval[b];
  for (int l = nb + t; l < MAXL; l += 64) posk[b * MAXL + l] = -1;
}

// ---------------------------------------------------------------------------
// fused fp32->bf16 for q_src/k_src/v_src. grid = (nq+nk+nv)/4/256 blocks.
__global__ __launch_bounds__(256) void cvt3(const float* __restrict__ q,
                                            const float* __restrict__ k,
                                            const float* __restrict__ v,
                                            unsigned short* __restrict__ oq,
                                            unsigned short* __restrict__ ok,
                                            unsigned short* __restrict__ ov) {
  const int nq = BB * MAXL * DD / 4, nk = BB * SS * DD / 4;
  int idx = blockIdx.x * 256 + threadIdx.x;
  const float* src; unsigned short* dst; int off;
  if (idx < nq) { src = q; dst = oq; off = idx; }
  else if (idx < nq + nk) { src = k; dst = ok; off = idx - nq; }
  else { src = v; dst = ov; off = idx - nq - nk; }
  float4 vv = ((const float4*)src)[off];
  ushort4 h;
  h.x = f2bf(vv.x); h.y = f2bf(vv.y); h.z = f2bf(vv.z); h.w = f2bf(vv.w);
  ((ushort4*)dst)[off] = h;
}

// ---------------------------------------------------------------------------
// 4 weight matrices [2048][2048] fp32 -> bf16 transposed, z picks the matrix.
__global__ __launch_bounds__(256) void transpose_w4(const float* __restrict__ w0,
    const float* __restrict__ w1, const float* __restrict__ w2, const float* __restrict__ w3,
    unsigned short* __restrict__ o0, unsigned short* __restrict__ o1,
    unsigned short* __restrict__ o2, unsigned short* __restrict__ o3) {
  __shared__ __align__(16) unsigned short tile[64 * 76];
  const float* W; unsigned short* Wt;
  switch (blockIdx.z) {
    case 0: W = w0; Wt = o0; break;
    case 1: W = w1; Wt = o1; break;
    case 2: W = w2; Wt = o2; break;
    default: W = w3; Wt = o3; break;
  }
  int tx = threadIdx.x;
  int K0 = blockIdx.y * 64, N0 = blockIdx.x * 64;
  #pragma unroll
  for (int i = 0; i < 4; i++) {
    int r = (tx >> 4) + i * 16, c4 = (tx & 15) * 4;
    float4 v = *(const float4*)&W[(size_t)(K0 + r) * DD + N0 + c4];
    ushort4 h;
    h.x = f2bf(v.x); h.y = f2bf(v.y); h.z = f2bf(v.z); h.w = f2bf(v.w);
    *(ushort4*)&tile[r * 76 + c4] = h;
  }
  __syncthreads();
  #pragma unroll
  for (int i = 0; i < 4; i++) {
    int n = (tx >> 4) + i * 16, k4 = (tx & 15) * 4;
    ushort4 h;
    h.x = tile[(k4 + 0) * 76 + n];
    h.y = tile[(k4 + 1) * 76 + n];
    h.z = tile[(k4 + 2) * 76 + n];
    h.w = tile[(k4 + 3) * 76 + n];
    *(ushort4*)&Wt[(size_t)(N0 + n) * DD + K0 + k4] = h;
  }
}

// ---------------------------------------------------------------------------
// bf16 GEMM, 128x128 tile, BK=32, global_load_lds staging.
// mode 0: head-split bf16 [b][h][l][128] (LDS-bounce, coalesced dwordx4)
// mode 1: fp32 row-major [M][N] (direct)
// mode 2: V^T bf16 [b][h][d][S] (LDS-bounce transposed, coalesced dwordx4)
__global__ __launch_bounds__(256) void gemm_bt(const unsigned short* __restrict__ A,
                                               const unsigned short* __restrict__ Bt,
                                               void* __restrict__ Cp,
                                               int M, int N, int K, int mode, int Lbits) {
  __shared__ __align__(16) unsigned short buf[4 * 4352];  // 34.8 KB (epilogue bounce)
  unsigned short* As = buf;          // 128*32
  unsigned short* Bs = buf + 4096;   // 128*32
  const int tid = threadIdx.x;
  const int lane = tid & 63, quad = lane >> 4, c = lane & 15;
  const int w = tid >> 6;
  const int wm = (w >> 1) * 64, wn = (w & 1) * 64;
  const size_t tm = (size_t)blockIdx.y * 128, tn = (size_t)blockIdx.x * 128;

  f32x4 acc[4][4] = {};

  const int srow = tid >> 2, scol = (tid & 3) * 8;
  const unsigned short* ga = A + (tm + srow) * K + scol;
  const unsigned short* gb = Bt + (tn + srow) * K + scol;
  unsigned short* la = &As[tid * 8];
  unsigned short* lb = &Bs[tid * 8];

  for (int kk = 0; kk < K; kk += 32) {
    gl_lds16(ga + kk, la);
    gl_lds16(ga + kk + (size_t)64 * K, la + 2048);
    gl_lds16(gb + kk, lb);
    gl_lds16(gb + kk + (size_t)64 * K, lb + 2048);
    __syncthreads();
    bf16x8 af[4], bfr[4];
    #pragma unroll
    for (int i = 0; i < 4; i++) af[i] = ldfrag(&As[(wm + i * 16 + c) * 32 + quad * 8]);
    #pragma unroll
    for (int j = 0; j < 4; j++) bfr[j] = ldfrag(&Bs[(wn + j * 16 + c) * 32 + quad * 8]);
    #pragma unroll
    for (int i = 0; i < 4; i++)
      #pragma unroll
      for (int j = 0; j < 4; j++)
        acc[i][j] = __builtin_amdgcn_mfma_f32_16x16x32_bf16(af[i], bfr[j], acc[i][j], 0, 0, 0);
    __syncthreads();
  }
  // after final barrier all staging reads are done; buf is reusable per-wave

  if (mode == 1) {
    float* Cf = (float*)Cp;
    #pragma unroll
    for (int i = 0; i < 4; i++)
      #pragma unroll
      for (int j = 0; j < 4; j++)
        #pragma unroll
        for (int r = 0; r < 4; r++) {
          size_t m = tm + wm + i * 16 + quad * 4 + r;
          size_t n = tn + wn + j * 16 + c;
          Cf[m * N + n] = acc[i][j][r];
        }
    return;
  }
  unsigned short* Cb = (unsigned short*)Cp;
  unsigned short* ep = buf + w * 4352;   // per-wave 64x68 bounce tile
  if (mode == 0) {
    // stage [m][n]
    #pragma unroll
    for (int i = 0; i < 4; i++)
      #pragma unroll
      for (int j = 0; j < 4; j++)
        #pragma unroll
        for (int r = 0; r < 4; r++)
          ep[(i * 16 + quad * 4 + r) * 68 + j * 16 + c] = f2bf(acc[i][j][r]);
    const size_t Lmask = ((size_t)1 << Lbits) - 1;
    #pragma unroll
    for (int it = 0; it < 8; it++) {
      int chunk = it * 64 + lane;
      int ml = chunk >> 3, nc = (chunk & 7) * 8;
      uint4 val = *(const uint4*)&ep[ml * 68 + nc];
      size_t m = tm + wm + ml, n = tn + wn + nc;
      size_t b = m >> Lbits, l = m & Lmask, h = n >> 7, d = n & 127;
      *(uint4*)&Cb[(((b * HH + h) << Lbits) + l) * 128 + d] = val;
    }
  } else {
    // mode 2: stage transposed [n][m], write V^T [b][h][d][S]
    #pragma unroll
    for (int i = 0; i < 4; i++)
      #pragma unroll
      for (int j = 0; j < 4; j++)
        #pragma unroll
        for (int r = 0; r < 4; r++)
          ep[(j * 16 + c) * 68 + i * 16 + quad * 4 + r] = f2bf(acc[i][j][r]);
    #pragma unroll
    for (int it = 0; it < 8; it++) {
      int chunk = it * 64 + lane;
      int nl = chunk >> 3, mc = (chunk & 7) * 8;
      uint4 val = *(const uint4*)&ep[nl * 68 + mc];
      size_t n = tn + wn + nl, m = tm + wm + mc;
      size_t b = m >> 11, s = m & 2047, h = n >> 7, d = n & 127;
      *(uint4*)&Cb[((b * HH + h) * 128 + d) * SS + s] = val;
    }
  }
}

// ---------------------------------------------------------------------------
// fused RoPE: first Nq threads handle Q (trimmed positions), rest handle K.
__global__ __launch_bounds__(256) void rope2(unsigned short* __restrict__ xq,
                                             unsigned short* __restrict__ xk,
                                             const int* __restrict__ posk) {
  const int Nq = BB * HH * MAXL * 64;
  int gid = blockIdx.x * 256 + threadIdx.x;
  unsigned short* x; int Lbits, idx, use_posk;
  if (gid < Nq) { x = xq; Lbits = 10; use_posk = 1; idx = gid; }
  else { x = xk; Lbits = 11; use_posk = 0; idx = gid - Nq; }
  int d = idx & 63;
  int rest = idx >> 6;
  int l = rest & ((1 << Lbits) - 1);
  int bh = rest >> Lbits;
  int b = bh >> 4;
  int p = use_posk ? posk[(b << 10) + l] : l;
  float ang = (float)p * __expf(-(float)d * 0.14391156831212787f); // ln(1e4)/64
  float sn, cs;
  __sincosf(ang, &sn, &cs);
  size_t base = (size_t)rest * 128;
  float x1 = bf2f(x[base + d]), x2 = bf2f(x[base + d + 64]);
  x[base + d]      = f2bf(x1 * cs - x2 * sn);
  x[base + d + 64] = f2bf(x2 * cs + x1 * sn);
}

// ---------------------------------------------------------------------------
// Flash attention. Grid: (bh 64, qtile 16) — bh fastest so all q-tiles of one
// bh map to the same XCD (round-robin by linear block id) for K/V L2 reuse.
// K and V^T staged via global_load_lds with XOR-swizzled source chunks:
// LDS slot (row, ch) holds global chunk (row, ch ^ (row&7)) -> b128 frag reads
// are perfectly bank-spread. Q fragments live in registers.
__global__ __launch_bounds__(256) void attn_kernel(const unsigned short* __restrict__ qp,
                                                   const unsigned short* __restrict__ kp,
                                                   const unsigned short* __restrict__ vtp,
                                                   const int* __restrict__ posk,
                                                   const int* __restrict__ nval,
                                                   unsigned short* __restrict__ ctx) {
  __shared__ __align__(16) unsigned short k_s[64 * 128];   // [s][d] swizzled
  __shared__ __align__(16) unsigned short vt_s[128 * 64];  // [d][s] swizzled
  __shared__ __align__(16) unsigned short p_s[4 * 16 * 72];
  __shared__ int km_s[64];

  const int tid = threadIdx.x;
  const int w = tid >> 6, lane = tid & 63, quad = lane >> 4, c = lane & 15;
  const int bh = blockIdx.x, b = bh >> 4, h = bh & 15;
  const int qbase = blockIdx.y * 64;
  const int nb = nval[b];

  if (tid < 64) {
    int l = qbase + tid;
    km_s[tid] = (l < nb) ? posk[(b << 10) + l] : -1;
  }
  __syncthreads();

  // Q fragments in registers (A-layout: m = c, k = ks*32 + quad*8 + j)
  const unsigned short* qg = qp + (((size_t)bh << 10) + qbase) * 128;
  bf16x8 aq[4];
  #pragma unroll
  for (int ks = 0; ks < 4; ks++)
    aq[ks] = ldfrag(&qg[(size_t)(w * 16 + c) * 128 + ks * 32 + quad * 8]);

  int lv = nb - 1 - qbase; lv = lv > 63 ? 63 : lv;
  const int tile_kmax = (lv >= 0) ? km_s[lv] : -1;
  const int nkt = (tile_kmax >= 0) ? ((tile_kmax >> 6) + 1) : 0;

  int km[4];
  #pragma unroll
  for (int r = 0; r < 4; r++) km[r] = km_s[w * 16 + quad * 4 + r];

  // staging source pointers (swizzle keys constant across the i-unroll)
  const int srow = tid >> 4;                       // K: s-local row 0..15 (+16i)
  const int kswz = (tid & 15) ^ (srow & 7);
  const unsigned short* kgp = kp + ((size_t)bh << 11) * 128 + (size_t)srow * 128 + kswz * 8;
  const int dvrow = tid >> 3;                      // V: d-local row 0..31 (+32i)
  const int vswz = (tid & 7) ^ (dvrow & 7);
  const unsigned short* vgp = vtp + ((size_t)bh * 128 + dvrow) * SS + vswz * 8;

  float m_i[4], l_i[4];
  #pragma unroll
  for (int r = 0; r < 4; r++) { m_i[r] = -1e30f; l_i[r] = 0.f; }
  f32x4 o[8];
  #pragma unroll
  for (int dj = 0; dj < 8; dj++) o[dj] = (f32x4){0.f, 0.f, 0.f, 0.f};

  for (int kt = 0; kt < nkt; kt++) {
    const int kb = kt * 64;
    __syncthreads();   // previous tile's LDS reads complete
    #pragma unroll
    for (int i = 0; i < 4; i++)
      gl_lds16(kgp + ((size_t)kb + i * 16) * 128, &k_s[(i * 256 + tid) * 8]);
    #pragma unroll
    for (int i = 0; i < 4; i++)
      gl_lds16(vgp + (size_t)kb + (size_t)i * 32 * SS, &vt_s[(i * 256 + tid) * 8]);
    __syncthreads();   // drains vmcnt

    // S = Q K^T
    f32x4 sa[4];
    #pragma unroll
    for (int j = 0; j < 4; j++) {
      sa[j] = (f32x4){0.f, 0.f, 0.f, 0.f};
      #pragma unroll
      for (int ks = 0; ks < 4; ks++) {
        bf16x8 bk = ldfrag(&k_s[((j * 16 + c) << 7) + (((ks * 4 + quad) ^ (c & 7)) << 3)]);
        sa[j] = __builtin_amdgcn_mfma_f32_16x16x32_bf16(aq[ks], bk, sa[j], 0, 0, 0);
      }
    }

    // online softmax (rows live in quads; reduce over the 16 lanes of a quad)
    const float scale = 0.08838834764831843f;  // 1/sqrt(128)
    float mt[4] = {-1e30f, -1e30f, -1e30f, -1e30f};
    #pragma unroll
    for (int j = 0; j < 4; j++) {
      int key = kb + j * 16 + c;
      #pragma unroll
      for (int r = 0; r < 4; r++) {
        float v = (key <= km[r]) ? sa[j][r] * scale : -1e30f;
        sa[j][r] = v;
        mt[r] = fmaxf(mt[r], v);
      }
    }
    #pragma unroll
    for (int r = 0; r < 4; r++)
      for (int off = 1; off < 16; off <<= 1)
        mt[r] = fmaxf(mt[r], __shfl_xor(mt[r], off, 16));
    float al[4], rs[4];
    #pragma unroll
    for (int r = 0; r < 4; r++) {
      float mn = fmaxf(m_i[r], mt[r]);
      al[r] = __expf(m_i[r] - mn);
      m_i[r] = mn;
      rs[r] = 0.f;
    }
    #pragma unroll
    for (int j = 0; j < 4; j++)
      #pragma unroll
      for (int r = 0; r < 4; r++) {
        float pv = __expf(sa[j][r] - m_i[r]);
        sa[j][r] = pv;
        rs[r] += pv;
      }
    #pragma unroll
    for (int r = 0; r < 4; r++) {
      for (int off = 1; off < 16; off <<= 1) rs[r] += __shfl_xor(rs[r], off, 16);
      l_i[r] = l_i[r] * al[r] + rs[r];
    }
    #pragma unroll
    for (int dj = 0; dj < 8; dj++)
      #pragma unroll
      for (int r = 0; r < 4; r++) o[dj][r] *= al[r];

    // P: C-layout -> LDS -> A-layout (per-wave region)
    #pragma unroll
    for (int j = 0; j < 4; j++)
      #pragma unroll
      for (int r = 0; r < 4; r++)
        p_s[w * 1152 + (quad * 4 + r) * 72 + j * 16 + c] = f2bf(sa[j][r]);

    #pragma unroll
    for (int ks2 = 0; ks2 < 2; ks2++) {
      bf16x8 ap = ldfrag(&p_s[w * 1152 + c * 72 + ks2 * 32 + quad * 8]);
      #pragma unroll
      for (int dj = 0; dj < 8; dj++) {
        bf16x8 bv = ldfrag(&vt_s[((dj * 16 + c) << 6) + (((ks2 * 4 + quad) ^ (c & 7)) << 3)]);
        o[dj] = __builtin_amdgcn_mfma_f32_16x16x32_bf16(ap, bv, o[dj], 0, 0, 0);
      }
    }
  }

  #pragma unroll
  for (int r = 0; r < 4; r++) {
    int l = qbase + w * 16 + quad * 4 + r;
    bool ok = (l < nb);
    float inv = ok ? (1.0f / l_i[r]) : 0.0f;
    #pragma unroll
    for (int dj = 0; dj < 8; dj++)
      ctx[(((size_t)b << 10) + l) * (size_t)DD + h * 128 + dj * 16 + c] =
          f2bf(ok ? o[dj][r] * inv : 0.0f);
  }
}

// ---------------------------------------------------------------------------
extern "C" void kernel_launch(void* const* d_in, const int* in_sizes, int n_in,
                              void* d_out, int out_size, void* d_ws, size_t ws_size,
                              hipStream_t stream) {
  const float* q_src = (const float*)d_in[0];
  const float* k_src = (const float*)d_in[1];
  const float* v_src = (const float*)d_in[2];
  const float* Wq = (const float*)d_in[3];
  const float* Wk = (const float*)d_in[4];
  const float* Wv = (const float*)d_in[5];
  const float* Wo = (const float*)d_in[6];
  const int* skip = (const int*)d_in[9];

  char* p = (char*)d_ws;
  auto alloc = [&](size_t bytes) -> char* {
    char* r = p;
    p += (bytes + 255) & ~(size_t)255;
    return r;
  };
  unsigned short* a_q  = (unsigned short*)alloc((size_t)BB * MAXL * DD * 2);
  unsigned short* a_k  = (unsigned short*)alloc((size_t)BB * SS * DD * 2);
  unsigned short* a_v  = (unsigned short*)alloc((size_t)BB * SS * DD * 2);
  unsigned short* wt_q = (unsigned short*)alloc((size_t)DD * DD * 2);
  unsigned short* wt_k = (unsigned short*)alloc((size_t)DD * DD * 2);
  unsigned short* wt_v = (unsigned short*)alloc((size_t)DD * DD * 2);
  unsigned short* wt_o = (unsigned short*)alloc((size_t)DD * DD * 2);
  unsigned short* q_pro = (unsigned short*)alloc((size_t)BB * HH * MAXL * DHD * 2);
  unsigned short* k_pro = (unsigned short*)alloc((size_t)BB * HH * SS * DHD * 2);
  unsigned short* v_t   = (unsigned short*)alloc((size_t)BB * HH * SS * DHD * 2);
  int* posk = (int*)alloc((size_t)BB * MAXL * 4);
  int* nval = (int*)alloc(64);
  unsigned short* ctx = a_q;  // a_q dead after Q projection

  build_pos<<<BB, 64, 0, stream>>>(skip, posk, nval);
  cvt3<<<(BB * MAXL * DD + 2 * BB * SS * DD) / (4 * 256), 256, 0, stream>>>(
      q_src, k_src, v_src, a_q, a_k, a_v);
  transpose_w4<<<dim3(32, 32, 4), 256, 0, stream>>>(Wq, Wk, Wv, Wo, wt_q, wt_k, wt_v, wt_o);

  gemm_bt<<<dim3(16, 32), 256, 0, stream>>>(a_q, wt_q, q_pro, BB * MAXL, DD, DD, 0, 10);
  gemm_bt<<<dim3(16, 64), 256, 0, stream>>>(a_k, wt_k, k_pro, BB * SS, DD, DD, 0, 11);
  gemm_bt<<<dim3(16, 64), 256, 0, stream>>>(a_v, wt_v, v_t, BB * SS, DD, DD, 2, 11);

  rope2<<<(BB * HH * (MAXL + SS) * 64) / 256, 256, 0, stream>>>(q_pro, k_pro, posk);

  attn_kernel<<<dim3(BB * HH, MAXL / 64), 256, 0, stream>>>(q_pro, k_pro, v_t, posk, nval, ctx);

  gemm_bt<<<dim3(16, 32), 256, 0, stream>>>(ctx, wt_o, d_out, BB * MAXL, DD, DD, 1, 0);
}